// Round 6
// baseline (540.882 us; speedup 1.0000x reference)
//
#include <hip/hip_runtime.h>
#include <hip/hip_bf16.h>

// NonLocalBlock3D, fp32 in/out, bf16 MFMA compute.
// B=2, C=128, IC=64, W=H=32, Z=128, NZ=64. n_pixels = 2048.
// R4 lesson: DMA staging fixed traffic (270MB floor) but 77.8KB LDS ->
// 2 blocks/CU -> 20.8% occupancy -> latency-bound (all pipes <25%).
// R5: 4-slot x 8KB in-place quarter RING (T3/T4 counted-vmcnt stream).
// PHASEA consumes c-quarters; after each quarter barrier, stream-quarter
// s+3 is DMA'd into the freed slot. Stream spans halves AND pixels ->
// DMA never drains. ys/gp union (17KB). LDS 51.9KB -> 3 blocks/CU.
// Bank fix: pre-swizzled DMA source z^=((c>>3)&1)<<4, same XOR at gather
// (4-way -> free 2-way). PPB=2, grid 1024, launch_bounds(256,3).

#define C_      128
#define IC_     64
#define Z_      128
#define NZ_     64
#define CSTRIDE 131072
#define NPIX    2048
#define PPB     2
#define NQ      (PPB * 8)   // stream quarters per block
#define YSTRIDE 68          // ys row stride in shorts (136B rows)

typedef __attribute__((ext_vector_type(8))) short short8;   // 8 bf16 (4 VGPRs)
typedef __attribute__((ext_vector_type(4))) float f32x4;

union S8 { short8 s; uint4 u4; uint2 u2[2]; unsigned short h[8]; };

__device__ __forceinline__ unsigned short f2b(float f) {
    union { __hip_bfloat16 h; unsigned short u; } cv;
    cv.h = __float2bfloat16(f);
    return cv.u;
}

__device__ __forceinline__ void gl16(const float* g, float* l) {
    // HBM -> LDS DMA, 16B/lane. LDS dest = wave-uniform base + lane*16.
    __builtin_amdgcn_global_load_lds(
        (const __attribute__((address_space(1))) void*)g,
        (__attribute__((address_space(3))) void*)l, 16, 0, 0);
}

#define WAITV4() asm volatile("s_waitcnt vmcnt(4)" ::: "memory")
#define BARL()   do { asm volatile("s_waitcnt lgkmcnt(0)" ::: "memory"); \
                      __builtin_amdgcn_s_barrier(); } while (0)

// ---------------------------------------------------------------------------
// Prep: weights -> bf16 in ws; fold BN into alpha/beta; collapse theta via cat_w.
__global__ void nlb_prep(
    const float* __restrict__ g_w,   const float* __restrict__ theta_w,
    const float* __restrict__ phi_w, const float* __restrict__ W_w,
    const float* __restrict__ g_b,   const float* __restrict__ theta_b,
    const float* __restrict__ phi_b, const float* __restrict__ cat_w,
    const float* __restrict__ W_b,   const float* __restrict__ bn_g,
    const float* __restrict__ bn_b,  const float* __restrict__ bn_m,
    const float* __restrict__ bn_v,
    unsigned short* __restrict__ wcat, unsigned short* __restrict__ Wwb,
    float* __restrict__ twp, float* __restrict__ alphap, float* __restrict__ betap,
    float* __restrict__ cbp, float* __restrict__ cw2p, float* __restrict__ tbp)
{
    const int t = threadIdx.x;
    for (int idx = t; idx < 128 * 128; idx += 256) {           // [oc 0..127][c]
        const int oc = idx >> 7, c = idx & 127;
        const float v = (oc < 64) ? g_w[oc * 128 + c] : phi_w[(oc - 64) * 128 + c];
        wcat[idx] = f2b(v);
    }
    for (int idx = t; idx < 128 * 64; idx += 256)              // [c][oc] same layout
        Wwb[idx] = f2b(W_w[idx]);
    if (t < 128) {
        float s = 0.f;
        for (int oc = 0; oc < 64; ++oc) s += cat_w[oc] * theta_w[oc * 128 + t];
        twp[t] = s;
        const float sc = bn_g[t] * rsqrtf(bn_v[t] + 1e-5f);
        alphap[t] = sc;
        betap[t]  = (W_b[t] - bn_m[t]) * sc + bn_b[t];
        cbp[t] = (t < 64) ? g_b[t] : phi_b[t - 64];
    }
    if (t < 64) cw2p[t] = cat_w[64 + t];
    if (t == 0) {
        float s = 0.f;
        for (int oc = 0; oc < 64; ++oc) s += cat_w[oc] * theta_b[oc];
        tbp[0] = s;
    }
}

// ---------------------------------------------------------------------------
__global__ __launch_bounds__(256, 3) void nlb_main(
    const float* __restrict__ x,
    const unsigned short* __restrict__ wcat,   // [128 oc][128 c] bf16 (g|phi)
    const unsigned short* __restrict__ Wwb,    // [128 c][64 oc] bf16
    const float* __restrict__ twp, const float* __restrict__ alphap,
    const float* __restrict__ betap, const float* __restrict__ cbp,
    const float* __restrict__ cw2p, const float* __restrict__ tbp,
    float* __restrict__ out)
{
    const int tid  = threadIdx.x;
    const int lane = tid & 63;
    const int wv   = tid >> 6;       // wave 0..3
    const int n16  = lane & 15;
    const int q    = lane >> 4;      // quad 0..3
    const int pix0 = blockIdx.x * PPB;

    __shared__ float xs[4 * 2048];           // ring: 4 slots x [32c][64z] fp32 (8KB)
    __shared__ unsigned short un[128 * YSTRIDE]; // union: gp [64][72] / ys [128][68]
    __shared__ float a_s[128], b_s[64];
    __shared__ float alpha_s[128], beta_s[128], cb_s[128], cw2_s[64];
    __shared__ unsigned short twb_s[128];    // tw in bf16 (a-column MFMA B-op)

    auto PBASE = [&](int pix) -> size_t {
        const int b  = pix >> 10;
        const int wh = pix & 1023;
        return (size_t)b * C_ * CSTRIDE + (size_t)wh * Z_;
    };

    // Issue DMA for stream quarter s (2 ops/wave). Source pre-swizzled:
    // LDS[slot][cl][z'] = x[c][z' ^ ((cl>>3)&1)<<4]  (z-bit4 XOR c-bit3).
    auto ISSUE_Q = [&](int s) {
        if (s >= NQ) return;
        const size_t gbase = PBASE(pix0 + (s >> 3));
        const int h = (s >> 2) & 1, kt = s & 3, slot = s & 3;
        #pragma unroll
        for (int it = 0; it < 2; ++it) {
            const int idx = it * 256 + tid;
            const int cl = idx >> 4, zq = idx & 15;
            const int zsw = (zq * 4) ^ (((cl >> 3) & 1) << 4);
            const float* g = &x[gbase + (size_t)(kt * 32 + cl) * CSTRIDE + h * 64 + zsw];
            float* l = xs + slot * 2048 + it * 1024 + wv * 256;
            gl16(g, l);
        }
    };

    const float tb = tbp[0];

    // A(h): quarter-ring consumption. acc[oct] persists across the 4 quarters.
    auto PHASEA = [&](int h, int qbase) {
        const int zl = 16 * wv + n16;            // A-frag m-row -> z
        const int zz = zl ^ ((q & 1) << 4);      // swizzled gather row
        f32x4 acc[8];
        #pragma unroll
        for (int oct = 0; oct < 8; ++oct) {
            const float bias = cb_s[oct * 16 + n16];
            acc[oct] = (f32x4){bias, bias, bias, bias};
        }
        f32x4 aacc = {tb, tb, tb, tb};
        #pragma unroll
        for (int kt = 0; kt < 4; ++kt) {
            const int s = qbase + kt;
            WAITV4();                            // quarter s arrived (per-wave DMA)
            BARL();                              // all waves' DMA arrived; slot s-1 free
            ISSUE_Q(s + 3);                      // refill freed slot, stays in flight
            const float* xsrc = xs + (s & 3) * 2048;
            S8 t;
            const int cl0 = q * 8;
            #pragma unroll
            for (int e = 0; e < 8; ++e)
                t.h[e] = f2b(xsrc[(cl0 + e) * 64 + zz]);
            const short8 af = t.s;
            S8 bfa;
            bfa.u4 = (n16 == 0) ? *(const uint4*)&twb_s[kt * 32 + q * 8]
                                : (uint4){0u, 0u, 0u, 0u};
            aacc = __builtin_amdgcn_mfma_f32_16x16x32_bf16(af, bfa.s, aacc, 0, 0, 0);
            #pragma unroll
            for (int oct = 0; oct < 8; ++oct) {
                const short8 bf = *(const short8*)&wcat[(oct * 16 + n16) * 128 + kt * 32 + q * 8];
                acc[oct] = __builtin_amdgcn_mfma_f32_16x16x32_bf16(af, bf, acc[oct], 0, 0, 0);
            }
        }
        // tail: a_i, pooled gp, b_j partials
        if (n16 == 0) {
            #pragma unroll
            for (int r = 0; r < 4; ++r)
                a_s[h * 64 + 16 * wv + q * 4 + r] = aacc[r];
        }
        float bsum0 = 0.f, bsum1 = 0.f;
        const int j0 = h * 32 + 8 * wv + 2 * q;
        #pragma unroll
        for (int oct = 0; oct < 8; ++oct) {
            const float p0 = fmaxf(acc[oct][0], acc[oct][1]);  // z-pair pool
            const float p1 = fmaxf(acc[oct][2], acc[oct][3]);
            const int oc = oct * 16 + n16;
            if (oct < 4) {                        // g half -> gp[oc][j] (union)
                un[oc * 72 + j0]     = f2b(p0);
                un[oc * 72 + j0 + 1] = f2b(p1);
            } else {                              // phi half -> b_j partials
                const float cw = cw2_s[oc - 64];
                bsum0 += cw * p0; bsum1 += cw * p1;
            }
        }
        #pragma unroll
        for (int m = 1; m < 16; m <<= 1) {
            bsum0 += __shfl_xor(bsum0, m);
            bsum1 += __shfl_xor(bsum1, m);
        }
        if (n16 == 0) b_s[j0]     = bsum0;
        if (n16 == 1) b_s[j0 + 1] = bsum1;
    };

    // ---- prologue: prime ring depth-3, fill small arrays ----
    ISSUE_Q(0); ISSUE_Q(1); ISSUE_Q(2);
    if (tid < 128) {
        alpha_s[tid] = alphap[tid]; beta_s[tid] = betap[tid];
        twb_s[tid] = f2b(twp[tid]); cb_s[tid] = cbp[tid];
    }
    if (tid < 64) cw2_s[tid] = cw2p[tid];
    // (first quarter's WAITV4+BARL covers smalls visibility)

    for (int pp = 0; pp < PPB; ++pp) {
        const size_t base = PBASE(pix0 + pp);

        PHASEA(0, pp * 8);
        PHASEA(1, pp * 8 + 4);
        BARL();                                    // gp, a_s, b_s published

        // ---- Phase B: y[i][oc'] = sum_j relu(a_i+b_j)/64 * gp[j][oc'] ----
        {
            const int i0 = 32 * wv;
            short8 bfrag[4][2];
            #pragma unroll
            for (int nt = 0; nt < 4; ++nt)
                #pragma unroll
                for (int k = 0; k < 2; ++k)
                    bfrag[nt][k] = *(const short8*)&un[(nt * 16 + n16) * 72 + k * 32 + q * 8];
            float bv[2][8];
            #pragma unroll
            for (int k = 0; k < 2; ++k)
                #pragma unroll
                for (int jj = 0; jj < 8; ++jj)
                    bv[k][jj] = b_s[k * 32 + q * 8 + jj];
            float ai[2];
            #pragma unroll
            for (int mt = 0; mt < 2; ++mt) ai[mt] = a_s[i0 + mt * 16 + n16];
            BARL();                                // gp reads done -> union reusable
            f32x4 acc[2][4];
            #pragma unroll
            for (int mt = 0; mt < 2; ++mt) {
                #pragma unroll
                for (int nt = 0; nt < 4; ++nt) acc[mt][nt] = (f32x4){0.f, 0.f, 0.f, 0.f};
                #pragma unroll
                for (int k = 0; k < 2; ++k) {
                    S8 fr;                         // f in A-frag layout, on the fly
                    #pragma unroll
                    for (int jj = 0; jj < 8; ++jj)
                        fr.h[jj] = f2b(fmaxf(ai[mt] + bv[k][jj], 0.f) * 0.015625f);
                    #pragma unroll
                    for (int nt = 0; nt < 4; ++nt)
                        acc[mt][nt] = __builtin_amdgcn_mfma_f32_16x16x32_bf16(
                            fr.s, bfrag[nt][k], acc[mt][nt], 0, 0, 0);
                }
            }
            #pragma unroll
            for (int mt = 0; mt < 2; ++mt)         // ys[i][oc] bf16 into union
                #pragma unroll
                for (int nt = 0; nt < 4; ++nt)
                    #pragma unroll
                    for (int r = 0; r < 4; ++r) {
                        const int i  = i0 + mt * 16 + q * 4 + r;
                        const int oc = nt * 16 + n16;
                        un[i * YSTRIDE + oc] = f2b(acc[mt][nt][r]);
                    }
        }
        BARL();                                    // ys published

        // ---- Phase C: out[c][z] = alpha_c*(W . y[z]) + beta_c + x[c][z] ----
        {
            const int zt0 = 2 * wv;                // wave's z ntiles
            short8 bC[2][2];
            #pragma unroll
            for (int zt = 0; zt < 2; ++zt)
                #pragma unroll
                for (int k = 0; k < 2; ++k) {
                    const int z = (zt0 + zt) * 16 + n16;
                    S8 t;   // 136B-strided rows: 8B-aligned -> 2x uint2
                    t.u2[0] = *(const uint2*)&un[z * YSTRIDE + k * 32 + q * 8];
                    t.u2[1] = *(const uint2*)&un[z * YSTRIDE + k * 32 + q * 8 + 4];
                    bC[zt][k] = t.s;
                }
            #pragma unroll
            for (int mt = 0; mt < 8; ++mt) {
                short8 aC[2];
                const int ca = mt * 16 + n16;
                #pragma unroll
                for (int k = 0; k < 2; ++k)
                    aC[k] = *(const short8*)&Wwb[ca * 64 + k * 32 + q * 8];
                float al[4], be[4];
                #pragma unroll
                for (int r = 0; r < 4; ++r) {
                    const int cr = mt * 16 + q * 4 + r;
                    al[r] = alpha_s[cr]; be[r] = beta_s[cr];
                }
                #pragma unroll
                for (int zt = 0; zt < 2; ++zt) {
                    f32x4 acc = {0.f, 0.f, 0.f, 0.f};
                    #pragma unroll
                    for (int k = 0; k < 2; ++k)
                        acc = __builtin_amdgcn_mfma_f32_16x16x32_bf16(aC[k], bC[zt][k], acc, 0, 0, 0);
                    const int z = (zt0 + zt) * 16 + n16;
                    #pragma unroll
                    for (int r = 0; r < 4; ++r) {
                        const int cr = mt * 16 + q * 4 + r;
                        const size_t gaddr = base + (size_t)cr * CSTRIDE + z;
                        out[gaddr] = acc[r] * al[r] + be[r] + x[gaddr];
                    }
                }
            }
        }
        // no pixel-end barrier: next pixel's first quarter BARL covers
        // (union next overwritten only at A-tail, 4 barriers later).
    }
}

// ---------------------------------------------------------------------------
extern "C" void kernel_launch(void* const* d_in, const int* in_sizes, int n_in,
                              void* d_out, int out_size, void* d_ws, size_t ws_size,
                              hipStream_t stream) {
    const float* x       = (const float*)d_in[0];
    const float* g_w     = (const float*)d_in[1];
    const float* g_b     = (const float*)d_in[2];
    const float* theta_w = (const float*)d_in[3];
    const float* theta_b = (const float*)d_in[4];
    const float* phi_w   = (const float*)d_in[5];
    const float* phi_b   = (const float*)d_in[6];
    const float* cat_w   = (const float*)d_in[7];
    const float* W_w     = (const float*)d_in[8];
    const float* W_b     = (const float*)d_in[9];
    const float* bn_g    = (const float*)d_in[10];
    const float* bn_b    = (const float*)d_in[11];
    const float* bn_m    = (const float*)d_in[12];
    const float* bn_v    = (const float*)d_in[13];
    float* out = (float*)d_out;

    char* ws = (char*)d_ws;     // needs ~52 KB of scratch
    unsigned short* wcat = (unsigned short*)ws;             // 32768 B
    unsigned short* Wwb  = (unsigned short*)(ws + 32768);   // 16384 B
    float* twp    = (float*)(ws + 49152);
    float* alphap = (float*)(ws + 49664);
    float* betap  = (float*)(ws + 50176);
    float* cbp    = (float*)(ws + 50688);
    float* cw2p   = (float*)(ws + 51200);
    float* tbp    = (float*)(ws + 51456);

    nlb_prep<<<dim3(1), dim3(256), 0, stream>>>(
        g_w, theta_w, phi_w, W_w, g_b, theta_b, phi_b, cat_w, W_b,
        bn_g, bn_b, bn_m, bn_v,
        wcat, Wwb, twp, alphap, betap, cbp, cw2p, tbp);

    nlb_main<<<dim3(NPIX / PPB), dim3(256), 0, stream>>>(
        x, wcat, Wwb, twp, alphap, betap, cbp, cw2p, tbp, out);
}

// Round 7
// 327.414 us; speedup vs baseline: 1.6520x; 1.6520x over previous
//
#include <hip/hip_runtime.h>
#include <hip/hip_bf16.h>

// NonLocalBlock3D, fp32 in/out, bf16 MFMA compute.
// B=2, C=128, IC=64, W=H=32, Z=128, NZ=64. n_pixels = 2048.
// R4 (best, 133us main): DMA staging via global_load_lds, counted vmcnt,
// PPB=4 grid 512, LDS 77.8KB, 2 blocks/CU.
// R5 lesson: quarter-ring counted-vmcnt mixed with Phase C's 128 vmem ops
// forces epilogue drains + sub-latency prefetch distance -> 310us. Reverted.
// R6: main = R4 byte-identical (control). PREP PARALLELIZED grid(1)->grid(33):
// harness dur minus main dur has been a CONSTANT ~210us across all rounds --
// attributed to the single-workgroup prep dispatch (1 CU busy, serial loops,
// cold weights). All prep work is element-parallel.

#define C_      128
#define IC_     64
#define Z_      128
#define NZ_     64
#define CSTRIDE 131072
#define NPIX    2048
#define PPB     4       // pixels per block; grid = 512 = 2 blocks/CU exact fill
#define YSTRIDE 68      // ys row stride in shorts (136B rows)

typedef __attribute__((ext_vector_type(8))) short short8;   // 8 bf16 (4 VGPRs)
typedef __attribute__((ext_vector_type(4))) float f32x4;

union S8 { short8 s; uint4 u4; uint2 u2[2]; unsigned short h[8]; };

__device__ __forceinline__ unsigned short f2b(float f) {
    union { __hip_bfloat16 h; unsigned short u; } cv;
    cv.h = __float2bfloat16(f);
    return cv.u;
}

__device__ __forceinline__ void gl16(const float* g, float* l) {
    // HBM -> LDS DMA, 16B/lane. LDS dest = wave-uniform base + lane*16.
    __builtin_amdgcn_global_load_lds(
        (const __attribute__((address_space(1))) void*)g,
        (__attribute__((address_space(3))) void*)l, 16, 0, 0);
}

// ---------------------------------------------------------------------------
// Prep (R6: parallel, grid 33): weights -> bf16 in ws; fold BN into alpha/beta;
// collapse theta via cat_w. Blocks 0-15: wcat. 16-31: Wwb. 32: scalar folds.
__global__ void nlb_prep(
    const float* __restrict__ g_w,   const float* __restrict__ theta_w,
    const float* __restrict__ phi_w, const float* __restrict__ W_w,
    const float* __restrict__ g_b,   const float* __restrict__ theta_b,
    const float* __restrict__ phi_b, const float* __restrict__ cat_w,
    const float* __restrict__ W_b,   const float* __restrict__ bn_g,
    const float* __restrict__ bn_b,  const float* __restrict__ bn_m,
    const float* __restrict__ bn_v,
    unsigned short* __restrict__ wcat, unsigned short* __restrict__ Wwb,
    float* __restrict__ twp, float* __restrict__ alphap, float* __restrict__ betap,
    float* __restrict__ cbp, float* __restrict__ cw2p, float* __restrict__ tbp)
{
    const int t  = threadIdx.x;
    const int bb = blockIdx.x;
    if (bb < 16) {                       // wcat: [oc 0..127][c], 1024 elems/block
        #pragma unroll
        for (int u = 0; u < 4; ++u) {
            const int idx = bb * 1024 + u * 256 + t;
            const int oc = idx >> 7, c = idx & 127;
            const float v = (oc < 64) ? g_w[oc * 128 + c] : phi_w[(oc - 64) * 128 + c];
            wcat[idx] = f2b(v);
        }
    } else if (bb < 32) {                // Wwb: [c][oc], 512 elems/block
        #pragma unroll
        for (int u = 0; u < 2; ++u) {
            const int idx = (bb - 16) * 512 + u * 256 + t;
            Wwb[idx] = f2b(W_w[idx]);
        }
    } else {                             // scalar folds
        if (t < 128) {
            float s = 0.f;
            for (int oc = 0; oc < 64; ++oc) s += cat_w[oc] * theta_w[oc * 128 + t];
            twp[t] = s;
            const float sc = bn_g[t] * rsqrtf(bn_v[t] + 1e-5f);
            alphap[t] = sc;
            betap[t]  = (W_b[t] - bn_m[t]) * sc + bn_b[t];
            cbp[t] = (t < 64) ? g_b[t] : phi_b[t - 64];
        }
        if (t < 64) cw2p[t] = cat_w[64 + t];
        if (t == 0) {
            float s = 0.f;
            for (int oc = 0; oc < 64; ++oc) s += cat_w[oc] * theta_b[oc];
            tbp[0] = s;
        }
    }
}

// ---------------------------------------------------------------------------
__global__ __launch_bounds__(256, 2) void nlb_main(
    const float* __restrict__ x,
    const unsigned short* __restrict__ wcat,   // [128 oc][128 c] bf16 (g|phi)
    const unsigned short* __restrict__ Wwb,    // [128 c][64 oc] bf16
    const float* __restrict__ twp, const float* __restrict__ alphap,
    const float* __restrict__ betap, const float* __restrict__ cbp,
    const float* __restrict__ cw2p, const float* __restrict__ tbp,
    float* __restrict__ out)
{
    const int tid  = threadIdx.x;
    const int lane = tid & 63;
    const int wv   = tid >> 6;       // wave 0..3
    const int n16  = lane & 15;
    const int q    = lane >> 4;      // quad 0..3
    const int pix0 = blockIdx.x * PPB;

    __shared__ float xs0[8192];                    // fp32 x-half h0: [c 128][z 64] linear
    __shared__ float xs1[8192];                    // fp32 x-half h1; aliased by ys after A1
    __shared__ unsigned short gp[64 * 72];         // [oc 64][j 64+8] bf16 (pooled g)
    __shared__ float a_s[128], b_s[64];
    __shared__ float alpha_s[128], beta_s[128], cb_s[128], cw2_s[64];
    __shared__ unsigned short twb_s[128];          // tw in bf16 (a-column MFMA B-op)
    unsigned short* ys = (unsigned short*)xs1;     // [i 128][oc 64+4] bf16

    auto PBASE = [&](int pix) -> size_t {
        const int b  = pix >> 10;
        const int wh = pix & 1023;
        return (size_t)b * C_ * CSTRIDE + (size_t)wh * Z_;
    };

    // Issue 8 global_load_lds (DMA) for one x-half into dst. No waits here.
    auto STAGE_ISSUE = [&](size_t gbase, int h, float* dst) {
        #pragma unroll
        for (int it = 0; it < 8; ++it) {
            const int idx = it * 256 + tid;            // chunk index (16B chunks)
            const int c = idx >> 4, zq = idx & 15;
            const float* g = &x[gbase + (size_t)c * CSTRIDE + h * 64 + zq * 4];
            float* l = dst + it * 1024 + wv * 256;     // wave-uniform base (floats)
            gl16(g, l);
        }
    };

    const float tb = tbp[0];

    auto PHASEA = [&](int h, const float* xsrc) {  // D[z][oc]=Wcat.x (+bias); pool; a_i
        const int zl = 16 * wv + n16;              // A: m=lane&15 -> z row
        short8 af[4];
        #pragma unroll
        for (int kt = 0; kt < 4; ++kt) {           // gather fp32, convert to bf16
            const int c0 = kt * 32 + q * 8;
            S8 t;
            #pragma unroll
            for (int e = 0; e < 8; ++e) t.h[e] = f2b(xsrc[(c0 + e) * 64 + zl]);
            af[kt] = t.s;
        }
        // a_i = tb + tw . x  via column-0 MFMA
        {
            f32x4 acc = {tb, tb, tb, tb};
            #pragma unroll
            for (int kt = 0; kt < 4; ++kt) {
                S8 bfa;
                bfa.u4 = (n16 == 0) ? *(const uint4*)&twb_s[kt * 32 + q * 8]
                                    : (uint4){0u, 0u, 0u, 0u};
                acc = __builtin_amdgcn_mfma_f32_16x16x32_bf16(af[kt], bfa.s, acc, 0, 0, 0);
            }
            if (n16 == 0) {                        // col 0 lanes hold a for rows q*4+r
                #pragma unroll
                for (int r = 0; r < 4; ++r)
                    a_s[h * 64 + 16 * wv + q * 4 + r] = acc[r];
            }
        }
        float bsum0 = 0.f, bsum1 = 0.f;
        const int j0 = h * 32 + 8 * wv + 2 * q;    // pooled j for (reg0,1); +1 for (2,3)
        #pragma unroll
        for (int oct = 0; oct < 8; ++oct) {
            const int oc = oct * 16 + n16;         // B: n=lane&15 -> oc col
            const float bias = cb_s[oc];
            f32x4 acc = {bias, bias, bias, bias};
            const unsigned short* wrow = wcat + oc * 128;
            #pragma unroll
            for (int k = 0; k < 4; ++k) {
                const short8 bf = *(const short8*)&wrow[k * 32 + q * 8];
                acc = __builtin_amdgcn_mfma_f32_16x16x32_bf16(af[k], bf, acc, 0, 0, 0);
            }
            const float p0 = fmaxf(acc[0], acc[1]);   // z-pair pool in-register
            const float p1 = fmaxf(acc[2], acc[3]);
            if (oct < 4) {                          // g half -> gp[oc][j]
                gp[oc * 72 + j0]     = f2b(p0);
                gp[oc * 72 + j0 + 1] = f2b(p1);
            } else {                                // phi half -> b_j partials
                const float cw = cw2_s[oc - 64];
                bsum0 += cw * p0; bsum1 += cw * p1;
            }
        }
        #pragma unroll
        for (int m = 1; m < 16; m <<= 1) {          // reduce over the 16 oc lanes
            bsum0 += __shfl_xor(bsum0, m);
            bsum1 += __shfl_xor(bsum1, m);
        }
        if (n16 == 0) b_s[j0]     = bsum0;          // each wave owns disjoint j
        if (n16 == 1) b_s[j0 + 1] = bsum1;
    };

    // ---- prologue: issue both halves of pixel 0, fill small arrays ----
    STAGE_ISSUE(PBASE(pix0), 0, xs0);   // 8 ops/wave
    STAGE_ISSUE(PBASE(pix0), 1, xs1);   // 8 ops/wave
    if (tid < 128) {
        alpha_s[tid] = alphap[tid]; beta_s[tid] = betap[tid];
        twb_s[tid] = f2b(twp[tid]); cb_s[tid] = cbp[tid];
    }
    if (tid < 64) cw2_s[tid] = cw2p[tid];

    for (int pp = 0; pp < PPB; ++pp) {
        const size_t base = PBASE(pix0 + pp);
        const bool pf = (pp + 1 < PPB);

        // wait h0 (leave the 8 h1 ops in flight)
        asm volatile("s_waitcnt vmcnt(8) lgkmcnt(0)" ::: "memory");
        __builtin_amdgcn_s_barrier();              // xs0 ready; smalls/prev-C done
        PHASEA(0, xs0);
        asm volatile("s_waitcnt lgkmcnt(0)" ::: "memory");
        __builtin_amdgcn_s_barrier();              // xs0 free
        if (pf) STAGE_ISSUE(PBASE(pix0 + pp + 1), 0, xs0);   // h0' under A1/B/C
        if (pf) { asm volatile("s_waitcnt vmcnt(8) lgkmcnt(0)" ::: "memory"); }
        else    { asm volatile("s_waitcnt vmcnt(0) lgkmcnt(0)" ::: "memory"); }
        __builtin_amdgcn_s_barrier();              // xs1 (h1) ready; h0' flying
        PHASEA(1, xs1);
        asm volatile("s_waitcnt lgkmcnt(0)" ::: "memory");
        __builtin_amdgcn_s_barrier();              // gp,a_s,b_s published; xs1 free

        // ---- Phase B: y[i][oc'] = sum_j relu(a_i+b_j)/64 * gp[j][oc'] ----
        {
            const int i0 = 32 * wv;
            short8 bfrag[4][2];
            #pragma unroll
            for (int nt = 0; nt < 4; ++nt)
                #pragma unroll
                for (int k = 0; k < 2; ++k)
                    bfrag[nt][k] = *(const short8*)&gp[(nt * 16 + n16) * 72 + k * 32 + q * 8];
            float bv[2][8];
            #pragma unroll
            for (int k = 0; k < 2; ++k)
                #pragma unroll
                for (int jj = 0; jj < 8; ++jj)
                    bv[k][jj] = b_s[k * 32 + q * 8 + jj];
            f32x4 acc[2][4];
            #pragma unroll
            for (int mt = 0; mt < 2; ++mt) {
                const float ai = a_s[i0 + mt * 16 + n16];
                #pragma unroll
                for (int nt = 0; nt < 4; ++nt) acc[mt][nt] = (f32x4){0.f, 0.f, 0.f, 0.f};
                #pragma unroll
                for (int k = 0; k < 2; ++k) {
                    S8 fr;                             // f in A-frag layout, on the fly
                    #pragma unroll
                    for (int jj = 0; jj < 8; ++jj)
                        fr.h[jj] = f2b(fmaxf(ai + bv[k][jj], 0.f) * 0.015625f);
                    #pragma unroll
                    for (int nt = 0; nt < 4; ++nt)
                        acc[mt][nt] = __builtin_amdgcn_mfma_f32_16x16x32_bf16(
                            fr.s, bfrag[nt][k], acc[mt][nt], 0, 0, 0);
                }
            }
            #pragma unroll
            for (int mt = 0; mt < 2; ++mt)             // ys[i][oc] bf16 into xs1 alias
                #pragma unroll
                for (int nt = 0; nt < 4; ++nt)
                    #pragma unroll
                    for (int r = 0; r < 4; ++r) {
                        const int i  = i0 + mt * 16 + q * 4 + r;
                        const int oc = nt * 16 + n16;
                        ys[i * YSTRIDE + oc] = f2b(acc[mt][nt][r]);
                    }
        }
        asm volatile("s_waitcnt lgkmcnt(0)" ::: "memory");
        __builtin_amdgcn_s_barrier();              // ys published

        // ---- Phase C: out[c][z] = alpha_c*(W . y[z]) + beta_c + x[c][z] ----
        {
            const int zt0 = 2 * wv;                    // wave's z ntiles
            short8 bC[2][2];
            #pragma unroll
            for (int zt = 0; zt < 2; ++zt)
                #pragma unroll
                for (int k = 0; k < 2; ++k) {
                    const int z = (zt0 + zt) * 16 + n16;
                    S8 t;   // rows are 136B-strided: 8B-aligned -> 2x uint2
                    t.u2[0] = *(const uint2*)&ys[z * YSTRIDE + k * 32 + q * 8];
                    t.u2[1] = *(const uint2*)&ys[z * YSTRIDE + k * 32 + q * 8 + 4];
                    bC[zt][k] = t.s;
                }
            #pragma unroll
            for (int mt = 0; mt < 8; ++mt) {
                short8 aC[2];
                const int ca = mt * 16 + n16;
                #pragma unroll
                for (int k = 0; k < 2; ++k)
                    aC[k] = *(const short8*)&Wwb[ca * 64 + k * 32 + q * 8];
                float al[4], be[4];
                #pragma unroll
                for (int r = 0; r < 4; ++r) {
                    const int cr = mt * 16 + q * 4 + r;
                    al[r] = alpha_s[cr]; be[r] = beta_s[cr];
                }
                #pragma unroll
                for (int zt = 0; zt < 2; ++zt) {
                    f32x4 acc = {0.f, 0.f, 0.f, 0.f};
                    #pragma unroll
                    for (int k = 0; k < 2; ++k)
                        acc = __builtin_amdgcn_mfma_f32_16x16x32_bf16(aC[k], bC[zt][k], acc, 0, 0, 0);
                    const int z = (zt0 + zt) * 16 + n16;
                    #pragma unroll
                    for (int r = 0; r < 4; ++r) {
                        const int cr = mt * 16 + q * 4 + r;
                        const size_t gaddr = base + (size_t)cr * CSTRIDE + z;
                        out[gaddr] = acc[r] * al[r] + be[r] + x[gaddr];
                    }
                }
            }
        }
        asm volatile("s_waitcnt lgkmcnt(0)" ::: "memory");
        __builtin_amdgcn_s_barrier();              // ys reads done; xs1 reusable
        if (pf) STAGE_ISSUE(PBASE(pix0 + pp + 1), 1, xs1);   // h1' under loop-top wait/A0
    }
}

// ---------------------------------------------------------------------------
extern "C" void kernel_launch(void* const* d_in, const int* in_sizes, int n_in,
                              void* d_out, int out_size, void* d_ws, size_t ws_size,
                              hipStream_t stream) {
    const float* x       = (const float*)d_in[0];
    const float* g_w     = (const float*)d_in[1];
    const float* g_b     = (const float*)d_in[2];
    const float* theta_w = (const float*)d_in[3];
    const float* theta_b = (const float*)d_in[4];
    const float* phi_w   = (const float*)d_in[5];
    const float* phi_b   = (const float*)d_in[6];
    const float* cat_w   = (const float*)d_in[7];
    const float* W_w     = (const float*)d_in[8];
    const float* W_b     = (const float*)d_in[9];
    const float* bn_g    = (const float*)d_in[10];
    const float* bn_b    = (const float*)d_in[11];
    const float* bn_m    = (const float*)d_in[12];
    const float* bn_v    = (const float*)d_in[13];
    float* out = (float*)d_out;

    char* ws = (char*)d_ws;     // needs ~52 KB of scratch
    unsigned short* wcat = (unsigned short*)ws;             // 32768 B
    unsigned short* Wwb  = (unsigned short*)(ws + 32768);   // 16384 B
    float* twp    = (float*)(ws + 49152);
    float* alphap = (float*)(ws + 49664);
    float* betap  = (float*)(ws + 50176);
    float* cbp    = (float*)(ws + 50688);
    float* cw2p   = (float*)(ws + 51200);
    float* tbp    = (float*)(ws + 51456);

    nlb_prep<<<dim3(33), dim3(256), 0, stream>>>(
        g_w, theta_w, phi_w, W_w, g_b, theta_b, phi_b, cat_w, W_b,
        bn_g, bn_b, bn_m, bn_v,
        wcat, Wwb, twp, alphap, betap, cbp, cw2p, tbp);

    nlb_main<<<dim3(NPIX / PPB), dim3(256), 0, stream>>>(
        x, wcat, Wwb, twp, alphap, betap, cbp, cw2p, tbp, out);
}